// Round 3
// baseline (4170.110 us; speedup 1.0000x reference)
//
#include <hip/hip_runtime.h>

// Sizes
#define T 70
#define B 64
#define E 512
#define H 512
#define V 10000
#define TB (T*B)            // 4480
#define SLOT (H*B)          // 32768 floats per (t) state slot
#define LOGITS_N (T*B*V)    // 44800000

__device__ __forceinline__ float ftanh(float x) {
    // tanh(x) = 1 - 2/(exp(2x)+1); saturates correctly at +/-inf
    float e = __expf(2.0f * x);
    return 1.0f - 2.0f / (e + 1.0f);
}

// ---------------------------------------------------------------------------
// 1) Embedding gather: X[t][b][e] (row-major) = emb_table[ids[t][b]][e]
// ---------------------------------------------------------------------------
__global__ __launch_bounds__(256) void gather_emb(const int* __restrict__ ids,
                                                  const float* __restrict__ emb,
                                                  float* __restrict__ X) {
    int i = blockIdx.x * 256 + threadIdx.x;       // float4 index
    if (i >= TB * (E / 4)) return;
    int tok = i >> 7;                             // E/4 = 128 float4 per token
    int e4 = i & 127;
    int id = ids[tok];
    ((float4*)X)[i] = ((const float4*)emb)[id * 128 + e4];
}

// ---------------------------------------------------------------------------
// 2) Weight transpose (one-time):
//    W0hT[k][n] = W0[n][512+k]   (512 x 512)
//    W1T [k][n] = W1[n][k]       (1024 x 512; k<512 = x-part, k>=512 = h-part)
//    Reads coalesced; writes scattered (absorbed by L2 write-combining).
// ---------------------------------------------------------------------------
__global__ __launch_bounds__(256) void transpose_w(const float* __restrict__ W0,
                                                   const float* __restrict__ W1,
                                                   float* __restrict__ W0hT,
                                                   float* __restrict__ W1T) {
    int i = blockIdx.x * 256 + threadIdx.x;
    if (i < 512 * 512) {                          // W0 h-part: n = i>>9, k = i&511
        int n = i >> 9, k = i & 511;
        W0hT[k * 512 + n] = W0[n * 1024 + 512 + k];
    }
    int j = i - 512 * 512;
    if (j >= 0 && j < 512 * 1024) {               // W1: n = j>>10, k = j&1023
        int n = j >> 10, k = j & 1023;
        W1T[k * 512 + n] = W1[n * 1024 + k];
    }
}

// ---------------------------------------------------------------------------
// 3) P0 = X @ W0x.T + b0   -> layout (T, B=64, N=512)  [n contiguous]
// ---------------------------------------------------------------------------
__global__ __launch_bounds__(256) void gemm_p0(const float* __restrict__ X,
                                               const float* __restrict__ W0,
                                               const float* __restrict__ b0v,
                                               float* __restrict__ P0) {
    __shared__ float As[32][68];   // [k][b]
    __shared__ float Ws[32][68];   // [k][n]
    int t = blockIdx.y;
    int n0 = blockIdx.x * 64;
    int tid = threadIdx.x;
    int bq = tid & 15;    // b block = bq*4
    int nq = tid >> 4;    // n local = nq*4
    const float* A = X + t * 64 * E;
    float acc[4][4] = {{0.f}};     // [b][n]

    for (int kc = 0; kc < 512; kc += 32) {
        for (int i = tid; i < 512; i += 256) {
            int bb = i >> 3, kq = i & 7;
            float4 a = *(const float4*)(A + bb * E + kc + kq * 4);
            As[kq*4+0][bb] = a.x; As[kq*4+1][bb] = a.y;
            As[kq*4+2][bb] = a.z; As[kq*4+3][bb] = a.w;
        }
        for (int i = tid; i < 512; i += 256) {
            int nn = i >> 3, kq = i & 7;
            float4 w = *(const float4*)(W0 + (size_t)(n0 + nn) * 1024 + kc + kq * 4);
            Ws[kq*4+0][nn] = w.x; Ws[kq*4+1][nn] = w.y;
            Ws[kq*4+2][nn] = w.z; Ws[kq*4+3][nn] = w.w;
        }
        __syncthreads();
#pragma unroll
        for (int kk = 0; kk < 32; kk++) {
            float4 a = *(const float4*)&As[kk][bq * 4];
            float4 w = *(const float4*)&Ws[kk][nq * 4];
            acc[0][0] += a.x*w.x; acc[0][1] += a.x*w.y; acc[0][2] += a.x*w.z; acc[0][3] += a.x*w.w;
            acc[1][0] += a.y*w.x; acc[1][1] += a.y*w.y; acc[1][2] += a.y*w.z; acc[1][3] += a.y*w.w;
            acc[2][0] += a.z*w.x; acc[2][1] += a.z*w.y; acc[2][2] += a.z*w.z; acc[2][3] += a.z*w.w;
            acc[3][0] += a.w*w.x; acc[3][1] += a.w*w.y; acc[3][2] += a.w*w.z; acc[3][3] += a.w*w.w;
        }
        __syncthreads();
    }
    int nb = n0 + nq * 4;
    float4 bo = *(const float4*)(b0v + nb);
#pragma unroll
    for (int i = 0; i < 4; i++) {
        int bb = bq * 4 + i;
        float4 r = make_float4(acc[i][0] + bo.x, acc[i][1] + bo.y,
                               acc[i][2] + bo.z, acc[i][3] + bo.w);
        *(float4*)(P0 + (size_t)t * SLOT + bb * 512 + nb) = r;
    }
}

// ---------------------------------------------------------------------------
// 4) Zero-sync per-column recurrence. Batch columns are independent through
//    both layers and all steps, so ONE block owns one batch column for the
//    whole chain. State (h0, h1 columns: 2x512 floats) lives in LDS; the only
//    synchronization is __syncthreads (3/step). No fences, no flags.
//    Weights stream from L2 (3 MB/step/block, shared by the 8 blocks/XCD).
//    Thread owns n0 = 2*tid, n0+1 (float2 weight loads, 4 FMA chains).
// ---------------------------------------------------------------------------
__global__ __launch_bounds__(256) void chain_col(const float* __restrict__ P0,
                                                 const float* __restrict__ hidden,
                                                 const float* __restrict__ W0hT,
                                                 const float* __restrict__ W1T,
                                                 const float* __restrict__ b1v,
                                                 float* __restrict__ H1,
                                                 float* __restrict__ out) {
    __shared__ float h0s[512];
    __shared__ float h1s[512];
    int tid = threadIdx.x;
    int b = blockIdx.x;
    int n0 = tid * 2;

    for (int i = tid; i < 512; i += 256) {
        h0s[i] = hidden[b * 512 + i];              // layer 0 init
        h1s[i] = hidden[SLOT + b * 512 + i];       // layer 1 init
    }
    __syncthreads();

    float2 bia = *(const float2*)(b1v + n0);

    for (int s = 0; s < T; s++) {
        // ---- layer 0: h0_new = tanh(P0[s] + W0h @ h0_old) ----
        float2 p = *(const float2*)(P0 + (size_t)s * SLOT + b * 512 + n0);
        float ax = p.x, ay = p.y, bx = 0.f, by = 0.f;
#pragma unroll 8
        for (int k = 0; k < 256; k++) {
            float h = h0s[k];
            float g = h0s[k + 256];
            float2 w = *(const float2*)(W0hT + (size_t)k * 512 + n0);
            float2 u = *(const float2*)(W0hT + (size_t)(k + 256) * 512 + n0);
            ax += w.x * h; ay += w.y * h;
            bx += u.x * g; by += u.y * g;
        }
        float h0n0 = ftanh(ax + bx), h0n1 = ftanh(ay + by);
        __syncthreads();                 // all reads of old h0s done
        h0s[n0] = h0n0; h0s[n0 + 1] = h0n1;
        __syncthreads();                 // new h0s visible

        // ---- layer 1: h1_new = tanh(b1 + W1x @ h0_new + W1h @ h1_old) ----
        float axx = bia.x, axy = bia.y, ahx = 0.f, ahy = 0.f;
#pragma unroll 8
        for (int k = 0; k < 512; k++) {
            float hx = h0s[k];
            float hh = h1s[k];
            float2 wx = *(const float2*)(W1T + (size_t)k * 512 + n0);
            float2 wh = *(const float2*)(W1T + (size_t)(k + 512) * 512 + n0);
            axx += wx.x * hx; axy += wx.y * hx;
            ahx += wh.x * hh; ahy += wh.y * hh;
        }
        float o0 = ftanh(axx + ahx), o1 = ftanh(axy + ahy);
        __syncthreads();                 // all reads of old h1s done
        h1s[n0] = o0; h1s[n0 + 1] = o1;
        *(float2*)(H1 + (size_t)s * SLOT + b * 512 + n0) = make_float2(o0, o1);
        // next iteration's first barrier protects h1s before it's read again
    }
    __syncthreads();

    // final hidden -> d_out tail, (L,B,H) row-major
    for (int i = tid; i < 512; i += 256) {
        out[LOGITS_N + b * 512 + i]        = h0s[i];
        out[LOGITS_N + SLOT + b * 512 + i] = h1s[i];
    }
}

// ---------------------------------------------------------------------------
// 5) logits[t][b][v] = tanh(H1[t] @ Wout.T + bout);  H1 layout (T, B, N)
// ---------------------------------------------------------------------------
__global__ __launch_bounds__(256) void gemm_logits(const float* __restrict__ H1,
                                                   const float* __restrict__ Wout,
                                                   const float* __restrict__ boutv,
                                                   float* __restrict__ out) {
    __shared__ float As[32][68];   // [k][b]
    __shared__ float Ws[32][68];   // [k][v]
    int t = blockIdx.y;
    int v0 = blockIdx.x * 64;
    int tid = threadIdx.x;
    int bq = tid & 15;
    int vq = tid >> 4;
    const float* A = H1 + (size_t)t * SLOT;
    float acc[4][4] = {{0.f}};

    for (int kc = 0; kc < 512; kc += 32) {
        for (int i = tid; i < 512; i += 256) {
            int bb = i >> 3, kq = i & 7;
            float4 a = *(const float4*)(A + bb * 512 + kc + kq * 4);
            As[kq*4+0][bb] = a.x; As[kq*4+1][bb] = a.y;
            As[kq*4+2][bb] = a.z; As[kq*4+3][bb] = a.w;
        }
        for (int i = tid; i < 512; i += 256) {
            int vv = i >> 3, kq = i & 7;
            int v = v0 + vv;
            float4 w = (v < V) ? *(const float4*)(Wout + (size_t)v * 512 + kc + kq * 4)
                               : make_float4(0.f, 0.f, 0.f, 0.f);
            Ws[kq*4+0][vv] = w.x; Ws[kq*4+1][vv] = w.y;
            Ws[kq*4+2][vv] = w.z; Ws[kq*4+3][vv] = w.w;
        }
        __syncthreads();
#pragma unroll
        for (int kk = 0; kk < 32; kk++) {
            float4 a = *(const float4*)&As[kk][bq * 4];
            float4 w = *(const float4*)&Ws[kk][vq * 4];
            acc[0][0] += a.x*w.x; acc[0][1] += a.x*w.y; acc[0][2] += a.x*w.z; acc[0][3] += a.x*w.w;
            acc[1][0] += a.y*w.x; acc[1][1] += a.y*w.y; acc[1][2] += a.y*w.z; acc[1][3] += a.y*w.w;
            acc[2][0] += a.z*w.x; acc[2][1] += a.z*w.y; acc[2][2] += a.z*w.z; acc[2][3] += a.z*w.w;
            acc[3][0] += a.w*w.x; acc[3][1] += a.w*w.y; acc[3][2] += a.w*w.z; acc[3][3] += a.w*w.w;
        }
        __syncthreads();
    }
    int vb = v0 + vq * 4;
    if (vb < V) {
        float4 bo = *(const float4*)(boutv + vb);
#pragma unroll
        for (int i = 0; i < 4; i++) {
            int b = bq * 4 + i;
            float4 r = make_float4(ftanh(acc[i][0] + bo.x),
                                   ftanh(acc[i][1] + bo.y),
                                   ftanh(acc[i][2] + bo.z),
                                   ftanh(acc[i][3] + bo.w));
            *(float4*)(out + ((size_t)t * 64 + b) * V + vb) = r;
        }
    }
}

// ---------------------------------------------------------------------------
extern "C" void kernel_launch(void* const* d_in, const int* in_sizes, int n_in,
                              void* d_out, int out_size, void* d_ws, size_t ws_size,
                              hipStream_t stream) {
    const int*   ids    = (const int*)d_in[0];
    const float* hidden = (const float*)d_in[1];
    const float* emb    = (const float*)d_in[2];
    const float* W0     = (const float*)d_in[3];
    const float* b0v    = (const float*)d_in[4];
    const float* W1     = (const float*)d_in[5];
    const float* b1v    = (const float*)d_in[6];
    const float* Wout   = (const float*)d_in[7];
    const float* boutv  = (const float*)d_in[8];
    float* out = (float*)d_out;
    float* ws  = (float*)d_ws;

    float* X    = ws;                  // TB*E            = 2,293,760
    float* P0   = ws + 2293760;        // T*SLOT          = 2,293,760
    float* H1   = ws + 4587520;        // T*SLOT          = 2,293,760
    float* W0hT = ws + 6881280;        // 512*512         =   262,144
    float* W1T  = ws + 7143424;        // 1024*512        =   524,288
                                       // end: 7,667,712 floats = 30.7 MB

    gather_emb<<<2240, 256, 0, stream>>>(ids, emb, X);
    transpose_w<<<3072, 256, 0, stream>>>(W0, W1, W0hT, W1T);
    gemm_p0<<<dim3(8, T), 256, 0, stream>>>(X, W0, b0v, P0);
    chain_col<<<64, 256, 0, stream>>>(P0, hidden, W0hT, W1T, b1v, H1, out);
    gemm_logits<<<dim3(157, T), 256, 0, stream>>>(H1, Wout, boutv, out);
}

// Round 4
// 3788.059 us; speedup vs baseline: 1.1009x; 1.1009x over previous
//
#include <hip/hip_runtime.h>

// Sizes
#define T 70
#define B 64
#define E 512
#define H 512
#define V 10000
#define TB (T*B)            // 4480
#define SLOT (H*B)          // 32768 floats per (t) state slot
#define LOGITS_N (T*B*V)    // 44800000

__device__ __forceinline__ float ftanh(float x) {
    // tanh(x) = 1 - 2/(exp(2x)+1); saturates correctly at +/-inf
    float e = __expf(2.0f * x);
    return 1.0f - 2.0f / (e + 1.0f);
}

// ---------------------------------------------------------------------------
// 1) Embedding gather: X[t][b][e] (row-major) = emb_table[ids[t][b]][e]
// ---------------------------------------------------------------------------
__global__ __launch_bounds__(256) void gather_emb(const int* __restrict__ ids,
                                                  const float* __restrict__ emb,
                                                  float* __restrict__ X) {
    int i = blockIdx.x * 256 + threadIdx.x;       // float4 index
    if (i >= TB * (E / 4)) return;
    int tok = i >> 7;                             // E/4 = 128 float4 per token
    int e4 = i & 127;
    int id = ids[tok];
    ((float4*)X)[i] = ((const float4*)emb)[id * 128 + e4];
}

// ---------------------------------------------------------------------------
// 2) One-time LDS-tiled transposes of the recurrent weight halves:
//    W0hT[k][n] = W0[n][512+k]   (512 x 512)
//    W1hT[k][n] = W1[n][512+k]   (512 x 512)
//    Both reads and writes coalesced via 64x64 LDS tile.
// ---------------------------------------------------------------------------
__global__ __launch_bounds__(256) void transpose_w(const float* __restrict__ W0,
                                                   const float* __restrict__ W1,
                                                   float* __restrict__ W0hT,
                                                   float* __restrict__ W1hT) {
    __shared__ float tile[64][65];
    int blk = blockIdx.x;            // [0,128): matrix = blk>>6, tile = blk&63
    int m  = blk >> 6;
    int ti = (blk & 63) >> 3;        // 8x8 grid of 64x64 tiles
    int tj = blk & 7;
    const float* W = m ? W1 : W0;
    float* WT      = m ? W1hT : W0hT;
    int r = threadIdx.x >> 6;        // 0..3
    int c = threadIdx.x & 63;
    for (int rr = r; rr < 64; rr += 4)
        tile[rr][c] = W[(size_t)(ti * 64 + rr) * 1024 + 512 + tj * 64 + c];
    __syncthreads();
    for (int rr = r; rr < 64; rr += 4)
        WT[(size_t)(tj * 64 + rr) * 512 + ti * 64 + c] = tile[c][rr];
}

// ---------------------------------------------------------------------------
// 3) P0 = X @ W0x.T + b0   -> layout (T, B=64, N=512)  [n contiguous]
// ---------------------------------------------------------------------------
__global__ __launch_bounds__(256) void gemm_p0(const float* __restrict__ X,
                                               const float* __restrict__ W0,
                                               const float* __restrict__ b0v,
                                               float* __restrict__ P0) {
    __shared__ float As[32][68];   // [k][b]
    __shared__ float Ws[32][68];   // [k][n]
    int t = blockIdx.y;
    int n0 = blockIdx.x * 64;
    int tid = threadIdx.x;
    int bq = tid & 15;    // b block = bq*4
    int nq = tid >> 4;    // n local = nq*4
    const float* A = X + t * 64 * E;
    float acc[4][4] = {{0.f}};     // [b][n]

    for (int kc = 0; kc < 512; kc += 32) {
        for (int i = tid; i < 512; i += 256) {
            int bb = i >> 3, kq = i & 7;
            float4 a = *(const float4*)(A + bb * E + kc + kq * 4);
            As[kq*4+0][bb] = a.x; As[kq*4+1][bb] = a.y;
            As[kq*4+2][bb] = a.z; As[kq*4+3][bb] = a.w;
        }
        for (int i = tid; i < 512; i += 256) {
            int nn = i >> 3, kq = i & 7;
            float4 w = *(const float4*)(W0 + (size_t)(n0 + nn) * 1024 + kc + kq * 4);
            Ws[kq*4+0][nn] = w.x; Ws[kq*4+1][nn] = w.y;
            Ws[kq*4+2][nn] = w.z; Ws[kq*4+3][nn] = w.w;
        }
        __syncthreads();
#pragma unroll
        for (int kk = 0; kk < 32; kk++) {
            float4 a = *(const float4*)&As[kk][bq * 4];
            float4 w = *(const float4*)&Ws[kk][nq * 4];
            acc[0][0] += a.x*w.x; acc[0][1] += a.x*w.y; acc[0][2] += a.x*w.z; acc[0][3] += a.x*w.w;
            acc[1][0] += a.y*w.x; acc[1][1] += a.y*w.y; acc[1][2] += a.y*w.z; acc[1][3] += a.y*w.w;
            acc[2][0] += a.z*w.x; acc[2][1] += a.z*w.y; acc[2][2] += a.z*w.z; acc[2][3] += a.z*w.w;
            acc[3][0] += a.w*w.x; acc[3][1] += a.w*w.y; acc[3][2] += a.w*w.z; acc[3][3] += a.w*w.w;
        }
        __syncthreads();
    }
    int nb = n0 + nq * 4;
    float4 bo = *(const float4*)(b0v + nb);
#pragma unroll
    for (int i = 0; i < 4; i++) {
        int bb = bq * 4 + i;
        float4 r = make_float4(acc[i][0] + bo.x, acc[i][1] + bo.y,
                               acc[i][2] + bo.z, acc[i][3] + bo.w);
        *(float4*)(P0 + (size_t)t * SLOT + bb * 512 + nb) = r;
    }
}

// ---------------------------------------------------------------------------
// 3b) P1 = H0 @ W1x.T + b1  -> layout (T, B, N).  A rows are length 512.
//     W1x = front half (k<512) of W1's rows.
// ---------------------------------------------------------------------------
__global__ __launch_bounds__(256) void gemm_p1(const float* __restrict__ H0,
                                               const float* __restrict__ W1,
                                               const float* __restrict__ b1v,
                                               float* __restrict__ P1) {
    __shared__ float As[32][68];   // [k][b]
    __shared__ float Ws[32][68];   // [k][n]
    int t = blockIdx.y;
    int n0 = blockIdx.x * 64;
    int tid = threadIdx.x;
    int bq = tid & 15;
    int nq = tid >> 4;
    const float* A = H0 + (size_t)t * SLOT;
    float acc[4][4] = {{0.f}};     // [b][n]

    for (int kc = 0; kc < 512; kc += 32) {
        for (int i = tid; i < 512; i += 256) {
            int bb = i >> 3, kq = i & 7;
            float4 a = *(const float4*)(A + bb * 512 + kc + kq * 4);
            As[kq*4+0][bb] = a.x; As[kq*4+1][bb] = a.y;
            As[kq*4+2][bb] = a.z; As[kq*4+3][bb] = a.w;
        }
        for (int i = tid; i < 512; i += 256) {
            int nn = i >> 3, kq = i & 7;
            float4 w = *(const float4*)(W1 + (size_t)(n0 + nn) * 1024 + kc + kq * 4);
            Ws[kq*4+0][nn] = w.x; Ws[kq*4+1][nn] = w.y;
            Ws[kq*4+2][nn] = w.z; Ws[kq*4+3][nn] = w.w;
        }
        __syncthreads();
#pragma unroll
        for (int kk = 0; kk < 32; kk++) {
            float4 a = *(const float4*)&As[kk][bq * 4];
            float4 w = *(const float4*)&Ws[kk][nq * 4];
            acc[0][0] += a.x*w.x; acc[0][1] += a.x*w.y; acc[0][2] += a.x*w.z; acc[0][3] += a.x*w.w;
            acc[1][0] += a.y*w.x; acc[1][1] += a.y*w.y; acc[1][2] += a.y*w.z; acc[1][3] += a.y*w.w;
            acc[2][0] += a.z*w.x; acc[2][1] += a.z*w.y; acc[2][2] += a.z*w.z; acc[2][3] += a.z*w.w;
            acc[3][0] += a.w*w.x; acc[3][1] += a.w*w.y; acc[3][2] += a.w*w.z; acc[3][3] += a.w*w.w;
        }
        __syncthreads();
    }
    int nb = n0 + nq * 4;
    float4 bo = *(const float4*)(b1v + nb);
#pragma unroll
    for (int i = 0; i < 4; i++) {
        int bb = bq * 4 + i;
        float4 r = make_float4(acc[i][0] + bo.x, acc[i][1] + bo.y,
                               acc[i][2] + bo.z, acc[i][3] + bo.w);
        *(float4*)(P1 + (size_t)t * SLOT + bb * 512 + nb) = r;
    }
}

// ---------------------------------------------------------------------------
// 4) Register-resident single-layer recurrence: h_new = tanh(P[s] + Wh@h_old)
//    One block per batch column (64 blocks x 1024 threads). The 1 MB of
//    recurrent weights for this column's layer is loaded into VGPRs ONCE
//    (128 float2 = 256 VGPR/thread), then 70 steps run with zero weight
//    traffic. State (512 floats) lives in LDS; only __syncthreads per step.
//    Thread (n2 = tid&255, kh = tid>>8): owns n = {2*n2, 2*n2+1}, K-quarter
//    kh*128..+128. Per step: 32 LDS broadcast float4 reads + 256 reg FMAs,
//    then a 4-way partial reduction by threads 0..255.
// ---------------------------------------------------------------------------
__global__ __launch_bounds__(1024, 4) void chain_reg(const float* __restrict__ P,
                                                     const float* __restrict__ hidden,
                                                     const float* __restrict__ Wt,
                                                     float* __restrict__ Hist,
                                                     float* __restrict__ out,
                                                     int layer) {
    __shared__ float hs[512];
    __shared__ float part[4][512];
    int tid = threadIdx.x;
    int b   = blockIdx.x;
    int n2  = tid & 255;
    int kh  = tid >> 8;
    int n0  = n2 * 2;
    int kbase = kh * 128;

    // one-time: weights into registers (static indices only -> stays in VGPRs)
    float2 w[128];
#pragma unroll
    for (int j = 0; j < 128; j++)
        w[j] = *(const float2*)(Wt + (size_t)(kbase + j) * 512 + n0);

    for (int i = tid; i < 512; i += 1024)
        hs[i] = hidden[layer * SLOT + b * 512 + i];
    __syncthreads();

    for (int s = 0; s < T; s++) {
        // reducer threads issue their P load early; latency hides under FMAs
        float2 pin = make_float2(0.f, 0.f);
        if (tid < 256)
            pin = *(const float2*)(P + (size_t)s * SLOT + b * 512 + n0);

        float ax = 0.f, ay = 0.f;
#pragma unroll
        for (int j = 0; j < 128; j += 4) {
            float4 h4 = *(const float4*)&hs[kbase + j];   // wave-uniform: LDS broadcast
            ax += w[j].x*h4.x + w[j+1].x*h4.y + w[j+2].x*h4.z + w[j+3].x*h4.w;
            ay += w[j].y*h4.x + w[j+1].y*h4.y + w[j+2].y*h4.z + w[j+3].y*h4.w;
        }
        *(float2*)&part[kh][n0] = make_float2(ax, ay);
        __syncthreads();
        if (tid < 256) {
            float2 p0 = *(const float2*)&part[0][n0];
            float2 p1 = *(const float2*)&part[1][n0];
            float2 p2 = *(const float2*)&part[2][n0];
            float2 p3 = *(const float2*)&part[3][n0];
            float o0 = ftanh(pin.x + p0.x + p1.x + p2.x + p3.x);
            float o1 = ftanh(pin.y + p0.y + p1.y + p2.y + p3.y);
            hs[n0] = o0; hs[n0 + 1] = o1;
            *(float2*)(Hist + (size_t)s * SLOT + b * 512 + n0) = make_float2(o0, o1);
        }
        __syncthreads();
    }

    // final hidden -> d_out tail, (L,B,H) row-major
    for (int i = tid; i < 512; i += 1024)
        out[LOGITS_N + layer * SLOT + b * 512 + i] = hs[i];
}

// ---------------------------------------------------------------------------
// 5) logits[t][b][v] = tanh(H1[t] @ Wout.T + bout);  H1 layout (T, B, N)
// ---------------------------------------------------------------------------
__global__ __launch_bounds__(256) void gemm_logits(const float* __restrict__ H1,
                                                   const float* __restrict__ Wout,
                                                   const float* __restrict__ boutv,
                                                   float* __restrict__ out) {
    __shared__ float As[32][68];   // [k][b]
    __shared__ float Ws[32][68];   // [k][v]
    int t = blockIdx.y;
    int v0 = blockIdx.x * 64;
    int tid = threadIdx.x;
    int bq = tid & 15;
    int vq = tid >> 4;
    const float* A = H1 + (size_t)t * SLOT;
    float acc[4][4] = {{0.f}};

    for (int kc = 0; kc < 512; kc += 32) {
        for (int i = tid; i < 512; i += 256) {
            int bb = i >> 3, kq = i & 7;
            float4 a = *(const float4*)(A + bb * 512 + kc + kq * 4);
            As[kq*4+0][bb] = a.x; As[kq*4+1][bb] = a.y;
            As[kq*4+2][bb] = a.z; As[kq*4+3][bb] = a.w;
        }
        for (int i = tid; i < 512; i += 256) {
            int vv = i >> 3, kq = i & 7;
            int v = v0 + vv;
            float4 w = (v < V) ? *(const float4*)(Wout + (size_t)v * 512 + kc + kq * 4)
                               : make_float4(0.f, 0.f, 0.f, 0.f);
            Ws[kq*4+0][vv] = w.x; Ws[kq*4+1][vv] = w.y;
            Ws[kq*4+2][vv] = w.z; Ws[kq*4+3][vv] = w.w;
        }
        __syncthreads();
#pragma unroll
        for (int kk = 0; kk < 32; kk++) {
            float4 a = *(const float4*)&As[kk][bq * 4];
            float4 w = *(const float4*)&Ws[kk][vq * 4];
            acc[0][0] += a.x*w.x; acc[0][1] += a.x*w.y; acc[0][2] += a.x*w.z; acc[0][3] += a.x*w.w;
            acc[1][0] += a.y*w.x; acc[1][1] += a.y*w.y; acc[1][2] += a.y*w.z; acc[1][3] += a.y*w.w;
            acc[2][0] += a.z*w.x; acc[2][1] += a.z*w.y; acc[2][2] += a.z*w.z; acc[2][3] += a.z*w.w;
            acc[3][0] += a.w*w.x; acc[3][1] += a.w*w.y; acc[3][2] += a.w*w.z; acc[3][3] += a.w*w.w;
        }
        __syncthreads();
    }
    int vb = v0 + vq * 4;
    if (vb < V) {
        float4 bo = *(const float4*)(boutv + vb);
#pragma unroll
        for (int i = 0; i < 4; i++) {
            int b = bq * 4 + i;
            float4 r = make_float4(ftanh(acc[i][0] + bo.x),
                                   ftanh(acc[i][1] + bo.y),
                                   ftanh(acc[i][2] + bo.z),
                                   ftanh(acc[i][3] + bo.w));
            *(float4*)(out + ((size_t)t * 64 + b) * V + vb) = r;
        }
    }
}

// ---------------------------------------------------------------------------
extern "C" void kernel_launch(void* const* d_in, const int* in_sizes, int n_in,
                              void* d_out, int out_size, void* d_ws, size_t ws_size,
                              hipStream_t stream) {
    const int*   ids    = (const int*)d_in[0];
    const float* hidden = (const float*)d_in[1];
    const float* emb    = (const float*)d_in[2];
    const float* W0     = (const float*)d_in[3];
    const float* b0v    = (const float*)d_in[4];
    const float* W1     = (const float*)d_in[5];
    const float* b1v    = (const float*)d_in[6];
    const float* Wout   = (const float*)d_in[7];
    const float* boutv  = (const float*)d_in[8];
    float* out = (float*)d_out;
    float* ws  = (float*)d_ws;

    // buffer reuse: X dead after gemm_p0 -> P1 overlays it;
    //               P0 dead after chain0 -> H1 overlays it.
    float* X    = ws;                  // TB*E   = 2,293,760   (later: P1)
    float* P0   = ws + 2293760;        // T*SLOT = 2,293,760   (later: H1)
    float* H0   = ws + 4587520;        // T*SLOT = 2,293,760
    float* W0hT = ws + 6881280;        // 512*512 = 262,144
    float* W1hT = ws + 7143424;        // 512*512 = 262,144
    float* P1   = X;                   // end: 7,405,568 floats = 29.6 MB
    float* H1   = P0;

    gather_emb<<<2240, 256, 0, stream>>>(ids, emb, X);
    transpose_w<<<128, 256, 0, stream>>>(W0, W1, W0hT, W1hT);
    gemm_p0<<<dim3(8, T), 256, 0, stream>>>(X, W0, b0v, P0);
    chain_reg<<<64, 1024, 0, stream>>>(P0, hidden, W0hT, H0, out, 0);
    gemm_p1<<<dim3(8, T), 256, 0, stream>>>(H0, W1, b1v, P1);
    chain_reg<<<64, 1024, 0, stream>>>(P1, hidden, W1hT, H1, out, 1);
    gemm_logits<<<dim3(157, T), 256, 0, stream>>>(H1, Wout, boutv, out);
}

// Round 5
// 1802.283 us; speedup vs baseline: 2.3138x; 2.1018x over previous
//
#include <hip/hip_runtime.h>

// Sizes
#define T 70
#define B 64
#define E 512
#define H 512
#define V 10000
#define TB (T*B)            // 4480
#define SLOT (H*B)          // 32768 floats per (t) state slot
#define LOGITS_N (T*B*V)    // 44800000

// chain_hyb weight partition (per 256-k half, per layer):
//   k-offsets [0,64)   -> VGPR   (32 float4/thread, 256 KB/layer)
//   k-offsets [64,92)  -> LDS    (28 rows x 512 n x 2 halves = 112 KB)
//   k-offsets [92,256) -> stream (82 float4/thread/step, 656 KB/layer)
#define WV_F 65536          // floats in VGPR section  (2*32*256 float4)
#define WL_F 28672          // floats in LDS section   (2*28*512)
#define WS_F4 41984         // float4 in stream section (2*82*256)
#define WLAYER 262144       // floats per layer (1 MB)

__device__ __forceinline__ float ftanh(float x) {
    // tanh(x) = 1 - 2/(exp(2x)+1); saturates correctly at +/-inf
    float e = __expf(2.0f * x);
    return 1.0f - 2.0f / (e + 1.0f);
}

// ---------------------------------------------------------------------------
// 1) Embedding gather: X[t][b][e] (row-major) = emb_table[ids[t][b]][e]
// ---------------------------------------------------------------------------
__global__ __launch_bounds__(256) void gather_emb(const int* __restrict__ ids,
                                                  const float* __restrict__ emb,
                                                  float* __restrict__ X) {
    int i = blockIdx.x * 256 + threadIdx.x;       // float4 index
    if (i >= TB * (E / 4)) return;
    int tok = i >> 7;                             // E/4 = 128 float4 per token
    int e4 = i & 127;
    int id = ids[tok];
    ((float4*)X)[i] = ((const float4*)emb)[id * 128 + e4];
}

// ---------------------------------------------------------------------------
// 2) One-time pack of the recurrent weight halves W{0,1}[n][512+k] into the
//    three chain_hyb sections (all destinations linear for L2 streaming):
//    Wv: [hq][j2][n2] float4 {W(n0,k),W(n1,k),W(n0,k+1),W(n1,k+1)}, k=hq*256+2*j2, j2<32
//    Wl: [hq][jr][n]  float,  k = hq*256+64+jr, jr<28
//    Ws: [hq][j2s][n2] float4, k = hq*256+92+2*j2s, j2s<82
// ---------------------------------------------------------------------------
__global__ __launch_bounds__(256) void pack_w(const float* __restrict__ W0,
                                              const float* __restrict__ W1,
                                              float* __restrict__ Wpk) {
    int g = blockIdx.x * 256 + threadIdx.x;       // [0, 174080)
    int l = g >= 87040;
    int u = g - l * 87040;
    const float* S = l ? W1 : W0;
    float* D = Wpk + l * WLAYER;

    if (u < 16384) {                              // Wv float4 units
        int n2 = u & 255, q = u >> 8;             // q = hq*32 + j2
        int j2 = q & 31, hq = q >> 5;
        int k = hq * 256 + 2 * j2;
        int n0 = 2 * n2;
        float2 r0 = *(const float2*)(S + (size_t)n0 * 1024 + 512 + k);
        float2 r1 = *(const float2*)(S + (size_t)(n0 + 1) * 1024 + 512 + k);
        ((float4*)D)[(hq * 32 + j2) * 256 + n2] = make_float4(r0.x, r1.x, r0.y, r1.y);
    } else if (u < 16384 + WS_F4) {               // Ws float4 units
        int v = u - 16384;
        int n2 = v & 255, q = v >> 8;             // q in [0,164) = hq*82 + j2s
        int j2s = q % 82, hq = q / 82;
        int k = hq * 256 + 92 + 2 * j2s;
        int n0 = 2 * n2;
        float2 r0 = *(const float2*)(S + (size_t)n0 * 1024 + 512 + k);
        float2 r1 = *(const float2*)(S + (size_t)(n0 + 1) * 1024 + 512 + k);
        ((float4*)D)[(WV_F + WL_F) / 4 + (hq * 82 + j2s) * 256 + n2] =
            make_float4(r0.x, r1.x, r0.y, r1.y);
    } else {                                      // Wl scalar units
        int w = u - (16384 + WS_F4);
        int n = w & 511, q = w >> 9;              // q in [0,56) = hq*28 + jr
        int jr = q % 28, hq = q / 28;
        int k = hq * 256 + 64 + jr;
        D[WV_F + (hq * 28 + jr) * 512 + n] = S[(size_t)n * 1024 + 512 + k];
    }
}

// ---------------------------------------------------------------------------
// 3) P0 = X @ W0x.T + b0   -> layout (T, B=64, N=512)  [n contiguous]
// ---------------------------------------------------------------------------
__global__ __launch_bounds__(256) void gemm_p0(const float* __restrict__ X,
                                               const float* __restrict__ W0,
                                               const float* __restrict__ b0v,
                                               float* __restrict__ P0) {
    __shared__ float As[32][68];   // [k][b]
    __shared__ float Ws[32][68];   // [k][n]
    int t = blockIdx.y;
    int n0 = blockIdx.x * 64;
    int tid = threadIdx.x;
    int bq = tid & 15;    // b block = bq*4
    int nq = tid >> 4;    // n local = nq*4
    const float* A = X + t * 64 * E;
    float acc[4][4] = {{0.f}};     // [b][n]

    for (int kc = 0; kc < 512; kc += 32) {
        for (int i = tid; i < 512; i += 256) {
            int bb = i >> 3, kq = i & 7;
            float4 a = *(const float4*)(A + bb * E + kc + kq * 4);
            As[kq*4+0][bb] = a.x; As[kq*4+1][bb] = a.y;
            As[kq*4+2][bb] = a.z; As[kq*4+3][bb] = a.w;
        }
        for (int i = tid; i < 512; i += 256) {
            int nn = i >> 3, kq = i & 7;
            float4 w = *(const float4*)(W0 + (size_t)(n0 + nn) * 1024 + kc + kq * 4);
            Ws[kq*4+0][nn] = w.x; Ws[kq*4+1][nn] = w.y;
            Ws[kq*4+2][nn] = w.z; Ws[kq*4+3][nn] = w.w;
        }
        __syncthreads();
#pragma unroll
        for (int kk = 0; kk < 32; kk++) {
            float4 a = *(const float4*)&As[kk][bq * 4];
            float4 w = *(const float4*)&Ws[kk][nq * 4];
            acc[0][0] += a.x*w.x; acc[0][1] += a.x*w.y; acc[0][2] += a.x*w.z; acc[0][3] += a.x*w.w;
            acc[1][0] += a.y*w.x; acc[1][1] += a.y*w.y; acc[1][2] += a.y*w.z; acc[1][3] += a.y*w.w;
            acc[2][0] += a.z*w.x; acc[2][1] += a.z*w.y; acc[2][2] += a.z*w.z; acc[2][3] += a.z*w.w;
            acc[3][0] += a.w*w.x; acc[3][1] += a.w*w.y; acc[3][2] += a.w*w.z; acc[3][3] += a.w*w.w;
        }
        __syncthreads();
    }
    int nb = n0 + nq * 4;
    float4 bo = *(const float4*)(b0v + nb);
#pragma unroll
    for (int i = 0; i < 4; i++) {
        int bb = bq * 4 + i;
        float4 r = make_float4(acc[i][0] + bo.x, acc[i][1] + bo.y,
                               acc[i][2] + bo.z, acc[i][3] + bo.w);
        *(float4*)(P0 + (size_t)t * SLOT + bb * 512 + nb) = r;
    }
}

// ---------------------------------------------------------------------------
// 3b) P1 = H0 @ W1x.T + b1  -> layout (T, B, N).  A rows are length 512.
// ---------------------------------------------------------------------------
__global__ __launch_bounds__(256) void gemm_p1(const float* __restrict__ H0,
                                               const float* __restrict__ W1,
                                               const float* __restrict__ b1v,
                                               float* __restrict__ P1) {
    __shared__ float As[32][68];   // [k][b]
    __shared__ float Ws[32][68];   // [k][n]
    int t = blockIdx.y;
    int n0 = blockIdx.x * 64;
    int tid = threadIdx.x;
    int bq = tid & 15;
    int nq = tid >> 4;
    const float* A = H0 + (size_t)t * SLOT;
    float acc[4][4] = {{0.f}};     // [b][n]

    for (int kc = 0; kc < 512; kc += 32) {
        for (int i = tid; i < 512; i += 256) {
            int bb = i >> 3, kq = i & 7;
            float4 a = *(const float4*)(A + bb * 512 + kc + kq * 4);
            As[kq*4+0][bb] = a.x; As[kq*4+1][bb] = a.y;
            As[kq*4+2][bb] = a.z; As[kq*4+3][bb] = a.w;
        }
        for (int i = tid; i < 512; i += 256) {
            int nn = i >> 3, kq = i & 7;
            float4 w = *(const float4*)(W1 + (size_t)(n0 + nn) * 1024 + kc + kq * 4);
            Ws[kq*4+0][nn] = w.x; Ws[kq*4+1][nn] = w.y;
            Ws[kq*4+2][nn] = w.z; Ws[kq*4+3][nn] = w.w;
        }
        __syncthreads();
#pragma unroll
        for (int kk = 0; kk < 32; kk++) {
            float4 a = *(const float4*)&As[kk][bq * 4];
            float4 w = *(const float4*)&Ws[kk][nq * 4];
            acc[0][0] += a.x*w.x; acc[0][1] += a.x*w.y; acc[0][2] += a.x*w.z; acc[0][3] += a.x*w.w;
            acc[1][0] += a.y*w.x; acc[1][1] += a.y*w.y; acc[1][2] += a.y*w.z; acc[1][3] += a.y*w.w;
            acc[2][0] += a.z*w.x; acc[2][1] += a.z*w.y; acc[2][2] += a.z*w.z; acc[2][3] += a.z*w.w;
            acc[3][0] += a.w*w.x; acc[3][1] += a.w*w.y; acc[3][2] += a.w*w.z; acc[3][3] += a.w*w.w;
        }
        __syncthreads();
    }
    int nb = n0 + nq * 4;
    float4 bo = *(const float4*)(b1v + nb);
#pragma unroll
    for (int i = 0; i < 4; i++) {
        int bb = bq * 4 + i;
        float4 r = make_float4(acc[i][0] + bo.x, acc[i][1] + bo.y,
                               acc[i][2] + bo.z, acc[i][3] + bo.w);
        *(float4*)(P1 + (size_t)t * SLOT + bb * 512 + nb) = r;
    }
}

// ---------------------------------------------------------------------------
// 4) Hybrid-resident single-layer recurrence: h_new = tanh(P[s] + Wh@h_old)
//    One block per batch column (64 blocks x 512 threads). Weights split:
//    256 KB in NAMED VGPRs (32 float4/thread; never an indexable array),
//    112 KB in LDS (copied once), 656 KB streamed from L2 each step (82
//    float4/thread, deep-unrolled for MLP). State (512 f) in LDS; the only
//    sync is 2x __syncthreads per step. Thread: n2 = tid&255 owns outputs
//    {2*n2, 2*n2+1}; hq = tid>>8 owns k-half [hq*256, hq*256+256).
// ---------------------------------------------------------------------------
#define RPT32(X) X(0) X(1) X(2) X(3) X(4) X(5) X(6) X(7) X(8) X(9) X(10) X(11) \
  X(12) X(13) X(14) X(15) X(16) X(17) X(18) X(19) X(20) X(21) X(22) X(23) \
  X(24) X(25) X(26) X(27) X(28) X(29) X(30) X(31)
#define RPT16P(X) X(0,0,1) X(1,2,3) X(2,4,5) X(3,6,7) X(4,8,9) X(5,10,11) \
  X(6,12,13) X(7,14,15) X(8,16,17) X(9,18,19) X(10,20,21) X(11,22,23) \
  X(12,24,25) X(13,26,27) X(14,28,29) X(15,30,31)

__global__ __launch_bounds__(512, 2) void chain_hyb(const float* __restrict__ P,
                                                    const float* __restrict__ hidden,
                                                    const float* __restrict__ Wp,
                                                    float* __restrict__ Hist,
                                                    float* __restrict__ out,
                                                    int layer) {
    __shared__ float lds_w[WL_F];     // 112 KB: [hq][jr][n]
    __shared__ float hs[512];
    __shared__ float2 part2[256];
    int tid = threadIdx.x;
    int b   = blockIdx.x;
    int n2  = tid & 255;
    int hq  = tid >> 8;               // wave-uniform
    int n0  = 2 * n2;

    // ---- one-time: VGPR section into 32 NAMED float4 registers ----
    const float4* wv = (const float4*)Wp + hq * (32 * 256) + n2;
#define DECLW(i) const float4 w##i = wv[(i) * 256];
    RPT32(DECLW)
#undef DECLW

    // ---- one-time: LDS section ----
    {
        const float4* wl4 = (const float4*)(Wp + WV_F);
        float4* l4 = (float4*)lds_w;
        for (int i = tid; i < WL_F / 4; i += 512) l4[i] = wl4[i];
    }
    hs[tid & 511] = hidden[layer * SLOT + b * 512 + (tid & 511)];
    __syncthreads();

    const float4* wsp = (const float4*)(Wp + WV_F + WL_F) + hq * (82 * 256) + n2;
    const float4* hs4 = (const float4*)hs;
    const float2* ldsw2 = (const float2*)lds_w;
    int hql4 = hq * 64;               // hs4 base for VGPR section
    int ksb  = hq * 256 + 92;         // hs base for streamed section

    for (int s = 0; s < T; s++) {
        float2 pin = make_float2(0.f, 0.f);
        if (hq == 0)
            pin = *(const float2*)(P + (size_t)s * SLOT + b * 512 + n0);

        float ax = 0.f, ay = 0.f;

        // streamed section first: loads issue early, FMAs below hide latency
#pragma unroll 16
        for (int j = 0; j < 82; j++) {
            float4 wv4 = wsp[j * 256];
            float2 h2 = *(const float2*)&hs[ksb + 2 * j];
            ax += wv4.x * h2.x + wv4.z * h2.y;
            ay += wv4.y * h2.x + wv4.w * h2.y;
        }

        // VGPR-resident section (no memory traffic)
#define FMAV(m, A, B2) { float4 h4 = hs4[hql4 + (m)]; \
        ax += w##A.x * h4.x + w##A.z * h4.y + w##B2.x * h4.z + w##B2.z * h4.w; \
        ay += w##A.y * h4.x + w##A.w * h4.y + w##B2.y * h4.z + w##B2.w * h4.w; }
        RPT16P(FMAV)
#undef FMAV

        // LDS-resident section
#pragma unroll
        for (int g = 0; g < 7; g++) {
            float4 h4 = hs4[hql4 + 16 + g];
            float2 l0 = ldsw2[(hq * 28 + 4 * g + 0) * 256 + n2];
            float2 l1 = ldsw2[(hq * 28 + 4 * g + 1) * 256 + n2];
            float2 l2 = ldsw2[(hq * 28 + 4 * g + 2) * 256 + n2];
            float2 l3 = ldsw2[(hq * 28 + 4 * g + 3) * 256 + n2];
            ax += l0.x * h4.x + l1.x * h4.y + l2.x * h4.z + l3.x * h4.w;
            ay += l0.y * h4.x + l1.y * h4.y + l2.y * h4.z + l3.y * h4.w;
        }

        if (hq) part2[n2] = make_float2(ax, ay);
        __syncthreads();
        if (hq == 0) {
            float2 pr = part2[n2];
            float o0 = ftanh(pin.x + ax + pr.x);
            float o1 = ftanh(pin.y + ay + pr.y);
            hs[n0] = o0; hs[n0 + 1] = o1;
            *(float2*)(Hist + (size_t)s * SLOT + b * 512 + n0) = make_float2(o0, o1);
        }
        __syncthreads();
    }

    // final hidden -> d_out tail, (L,B,H) row-major
    out[LOGITS_N + layer * SLOT + b * 512 + tid] = hs[tid];
}

// ---------------------------------------------------------------------------
// 5) logits[t][b][v] = tanh(H1[t] @ Wout.T + bout);  H1 layout (T, B, N)
// ---------------------------------------------------------------------------
__global__ __launch_bounds__(256) void gemm_logits(const float* __restrict__ H1,
                                                   const float* __restrict__ Wout,
                                                   const float* __restrict__ boutv,
                                                   float* __restrict__ out) {
    __shared__ float As[32][68];   // [k][b]
    __shared__ float Ws[32][68];   // [k][v]
    int t = blockIdx.y;
    int v0 = blockIdx.x * 64;
    int tid = threadIdx.x;
    int bq = tid & 15;
    int vq = tid >> 4;
    const float* A = H1 + (size_t)t * SLOT;
    float acc[4][4] = {{0.f}};

    for (int kc = 0; kc < 512; kc += 32) {
        for (int i = tid; i < 512; i += 256) {
            int bb = i >> 3, kq = i & 7;
            float4 a = *(const float4*)(A + bb * 512 + kc + kq * 4);
            As[kq*4+0][bb] = a.x; As[kq*4+1][bb] = a.y;
            As[kq*4+2][bb] = a.z; As[kq*4+3][bb] = a.w;
        }
        for (int i = tid; i < 512; i += 256) {
            int vv = i >> 3, kq = i & 7;
            int v = v0 + vv;
            float4 w = (v < V) ? *(const float4*)(Wout + (size_t)v * 512 + kc + kq * 4)
                               : make_float4(0.f, 0.f, 0.f, 0.f);
            Ws[kq*4+0][vv] = w.x; Ws[kq*4+1][vv] = w.y;
            Ws[kq*4+2][vv] = w.z; Ws[kq*4+3][vv] = w.w;
        }
        __syncthreads();
#pragma unroll
        for (int kk = 0; kk < 32; kk++) {
            float4 a = *(const float4*)&As[kk][bq * 4];
            float4 w = *(const float4*)&Ws[kk][vq * 4];
            acc[0][0] += a.x*w.x; acc[0][1] += a.x*w.y; acc[0][2] += a.x*w.z; acc[0][3] += a.x*w.w;
            acc[1][0] += a.y*w.x; acc[1][1] += a.y*w.y; acc[1][2] += a.y*w.z; acc[1][3] += a.y*w.w;
            acc[2][0] += a.z*w.x; acc[2][1] += a.z*w.y; acc[2][2] += a.z*w.z; acc[2][3] += a.z*w.w;
            acc[3][0] += a.w*w.x; acc[3][1] += a.w*w.y; acc[3][2] += a.w*w.z; acc[3][3] += a.w*w.w;
        }
        __syncthreads();
    }
    int vb = v0 + vq * 4;
    if (vb < V) {
        float4 bo = *(const float4*)(boutv + vb);
#pragma unroll
        for (int i = 0; i < 4; i++) {
            int b = bq * 4 + i;
            float4 r = make_float4(ftanh(acc[i][0] + bo.x),
                                   ftanh(acc[i][1] + bo.y),
                                   ftanh(acc[i][2] + bo.z),
                                   ftanh(acc[i][3] + bo.w));
            *(float4*)(out + ((size_t)t * 64 + b) * V + vb) = r;
        }
    }
}

// ---------------------------------------------------------------------------
extern "C" void kernel_launch(void* const* d_in, const int* in_sizes, int n_in,
                              void* d_out, int out_size, void* d_ws, size_t ws_size,
                              hipStream_t stream) {
    const int*   ids    = (const int*)d_in[0];
    const float* hidden = (const float*)d_in[1];
    const float* emb    = (const float*)d_in[2];
    const float* W0     = (const float*)d_in[3];
    const float* b0v    = (const float*)d_in[4];
    const float* W1     = (const float*)d_in[5];
    const float* b1v    = (const float*)d_in[6];
    const float* Wout   = (const float*)d_in[7];
    const float* boutv  = (const float*)d_in[8];
    float* out = (float*)d_out;
    float* ws  = (float*)d_ws;

    // buffer reuse: X dead after gemm_p0 -> P1 overlays it;
    //               P0 dead after chain0 -> H1 overlays it.
    float* X    = ws;                  // TB*E   = 2,293,760   (later: P1)
    float* P0   = ws + 2293760;        // T*SLOT = 2,293,760   (later: H1)
    float* H0   = ws + 4587520;        // T*SLOT = 2,293,760
    float* Wpk  = ws + 6881280;        // 2 * 262,144 = 524,288
    float* P1   = X;                   // end: 7,405,568 floats = 29.6 MB
    float* H1   = P0;

    gather_emb<<<2240, 256, 0, stream>>>(ids, emb, X);
    pack_w<<<680, 256, 0, stream>>>(W0, W1, Wpk);
    gemm_p0<<<dim3(8, T), 256, 0, stream>>>(X, W0, b0v, P0);
    chain_hyb<<<64, 512, 0, stream>>>(P0, hidden, Wpk, H0, out, 0);
    gemm_p1<<<dim3(8, T), 256, 0, stream>>>(H0, W1, b1v, P1);
    chain_hyb<<<64, 512, 0, stream>>>(P1, hidden, Wpk + WLAYER, H1, out, 1);
    gemm_logits<<<dim3(157, T), 256, 0, stream>>>(H1, Wout, boutv, out);
}

// Round 6
// 1387.757 us; speedup vs baseline: 3.0049x; 1.2987x over previous
//
#include <hip/hip_runtime.h>

// Sizes
#define T 70
#define B 64
#define E 512
#define H 512
#define V 10000
#define NP 10112            // V padded to 79*128 for the MFMA logits GEMM
#define TB (T*B)            // 4480
#define SLOT (H*B)          // 32768 floats per (t) state slot
#define LOGITS_N (T*B*V)    // 44800000

// chain_hyb weight partition (per 256-k half, per layer):
//   k-offsets [0,64)   -> VGPR   (32 float4/thread, 256 KB/layer)
//   k-offsets [64,92)  -> LDS    (28 rows x 512 n x 2 halves = 112 KB)
//   k-offsets [92,256) -> stream (82 float4/thread/step, 656 KB/layer)
#define WV_F 65536          // floats in VGPR section  (2*32*256 float4)
#define WL_F 28672          // floats in LDS section   (2*28*512)
#define WS_F4 41984         // float4 in stream section (2*82*256)
#define WLAYER 262144       // floats per layer (1 MB)

typedef __attribute__((ext_vector_type(8))) short bh8;   // 8 bf16 (4 VGPRs)
typedef __attribute__((ext_vector_type(4))) float f32x4; // MFMA accumulator

__device__ __forceinline__ float ftanh(float x) {
    // tanh(x) = 1 - 2/(exp(2x)+1); saturates correctly at +/-inf
    float e = __expf(2.0f * x);
    return 1.0f - 2.0f / (e + 1.0f);
}

__device__ __forceinline__ unsigned short f2bf(float x) {  // RNE fp32->bf16
    unsigned int u = __float_as_uint(x);
    u += 0x7FFFu + ((u >> 16) & 1u);
    return (unsigned short)(u >> 16);
}
__device__ __forceinline__ float bf2f(unsigned short h) {
    return __uint_as_float(((unsigned int)h) << 16);
}

// ---------------------------------------------------------------------------
// 1) Embedding gather: X[t][b][e] (row-major) = emb_table[ids[t][b]][e]
// ---------------------------------------------------------------------------
__global__ __launch_bounds__(256) void gather_emb(const int* __restrict__ ids,
                                                  const float* __restrict__ emb,
                                                  float* __restrict__ X) {
    int i = blockIdx.x * 256 + threadIdx.x;       // float4 index
    if (i >= TB * (E / 4)) return;
    int tok = i >> 7;                             // E/4 = 128 float4 per token
    int e4 = i & 127;
    int id = ids[tok];
    ((float4*)X)[i] = ((const float4*)emb)[id * 128 + e4];
}

// ---------------------------------------------------------------------------
// 2) One-time pack of the recurrent weight halves W{0,1}[n][512+k] into the
//    three chain_hyb sections (all destinations linear for L2 streaming).
// ---------------------------------------------------------------------------
__global__ __launch_bounds__(256) void pack_w(const float* __restrict__ W0,
                                              const float* __restrict__ W1,
                                              float* __restrict__ Wpk) {
    int g = blockIdx.x * 256 + threadIdx.x;       // [0, 174080)
    int l = g >= 87040;
    int u = g - l * 87040;
    const float* S = l ? W1 : W0;
    float* D = Wpk + l * WLAYER;

    if (u < 16384) {                              // Wv float4 units
        int n2 = u & 255, q = u >> 8;             // q = hq*32 + j2
        int j2 = q & 31, hq = q >> 5;
        int k = hq * 256 + 2 * j2;
        int n0 = 2 * n2;
        float2 r0 = *(const float2*)(S + (size_t)n0 * 1024 + 512 + k);
        float2 r1 = *(const float2*)(S + (size_t)(n0 + 1) * 1024 + 512 + k);
        ((float4*)D)[(hq * 32 + j2) * 256 + n2] = make_float4(r0.x, r1.x, r0.y, r1.y);
    } else if (u < 16384 + WS_F4) {               // Ws float4 units
        int v = u - 16384;
        int n2 = v & 255, q = v >> 8;             // q in [0,164) = hq*82 + j2s
        int j2s = q % 82, hq = q / 82;
        int k = hq * 256 + 92 + 2 * j2s;
        int n0 = 2 * n2;
        float2 r0 = *(const float2*)(S + (size_t)n0 * 1024 + 512 + k);
        float2 r1 = *(const float2*)(S + (size_t)(n0 + 1) * 1024 + 512 + k);
        ((float4*)D)[(WV_F + WL_F) / 4 + (hq * 82 + j2s) * 256 + n2] =
            make_float4(r0.x, r1.x, r0.y, r1.y);
    } else {                                      // Wl scalar units
        int w = u - (16384 + WS_F4);
        int n = w & 511, q = w >> 9;              // q in [0,56) = hq*28 + jr
        int jr = q % 28, hq = q / 28;
        int k = hq * 256 + 64 + jr;
        D[WV_F + (hq * 28 + jr) * 512 + n] = S[(size_t)n * 1024 + 512 + k];
    }
}

// ---------------------------------------------------------------------------
// 2b) One-time split of Wout (fp32 [V][512]) into bf16 hi/lo, zero-padded to
//     [NP][512] rows so the MFMA GEMM needs no N-guard in its inner loop.
// ---------------------------------------------------------------------------
__global__ __launch_bounds__(256) void split_w(const float* __restrict__ Wout,
                                               unsigned short* __restrict__ Whi,
                                               unsigned short* __restrict__ Wlo) {
    int i = blockIdx.x * 256 + threadIdx.x;       // [0, NP*512)
    if (i >= NP * 512) return;
    int v = i >> 9;
    float x = (v < V) ? Wout[i] : 0.f;
    unsigned short hi = f2bf(x);
    Whi[i] = hi;
    Wlo[i] = f2bf(x - bf2f(hi));
}

// ---------------------------------------------------------------------------
// 3) P0 = X @ W0x.T + b0   -> layout (T, B=64, N=512)  [n contiguous]
// ---------------------------------------------------------------------------
__global__ __launch_bounds__(256) void gemm_p0(const float* __restrict__ X,
                                               const float* __restrict__ W0,
                                               const float* __restrict__ b0v,
                                               float* __restrict__ P0) {
    __shared__ float As[32][68];   // [k][b]
    __shared__ float Ws[32][68];   // [k][n]
    int t = blockIdx.y;
    int n0 = blockIdx.x * 64;
    int tid = threadIdx.x;
    int bq = tid & 15;    // b block = bq*4
    int nq = tid >> 4;    // n local = nq*4
    const float* A = X + t * 64 * E;
    float acc[4][4] = {{0.f}};     // [b][n]

    for (int kc = 0; kc < 512; kc += 32) {
        for (int i = tid; i < 512; i += 256) {
            int bb = i >> 3, kq = i & 7;
            float4 a = *(const float4*)(A + bb * E + kc + kq * 4);
            As[kq*4+0][bb] = a.x; As[kq*4+1][bb] = a.y;
            As[kq*4+2][bb] = a.z; As[kq*4+3][bb] = a.w;
        }
        for (int i = tid; i < 512; i += 256) {
            int nn = i >> 3, kq = i & 7;
            float4 w = *(const float4*)(W0 + (size_t)(n0 + nn) * 1024 + kc + kq * 4);
            Ws[kq*4+0][nn] = w.x; Ws[kq*4+1][nn] = w.y;
            Ws[kq*4+2][nn] = w.z; Ws[kq*4+3][nn] = w.w;
        }
        __syncthreads();
#pragma unroll
        for (int kk = 0; kk < 32; kk++) {
            float4 a = *(const float4*)&As[kk][bq * 4];
            float4 w = *(const float4*)&Ws[kk][nq * 4];
            acc[0][0] += a.x*w.x; acc[0][1] += a.x*w.y; acc[0][2] += a.x*w.z; acc[0][3] += a.x*w.w;
            acc[1][0] += a.y*w.x; acc[1][1] += a.y*w.y; acc[1][2] += a.y*w.z; acc[1][3] += a.y*w.w;
            acc[2][0] += a.z*w.x; acc[2][1] += a.z*w.y; acc[2][2] += a.z*w.z; acc[2][3] += a.z*w.w;
            acc[3][0] += a.w*w.x; acc[3][1] += a.w*w.y; acc[3][2] += a.w*w.z; acc[3][3] += a.w*w.w;
        }
        __syncthreads();
    }
    int nb = n0 + nq * 4;
    float4 bo = *(const float4*)(b0v + nb);
#pragma unroll
    for (int i = 0; i < 4; i++) {
        int bb = bq * 4 + i;
        float4 r = make_float4(acc[i][0] + bo.x, acc[i][1] + bo.y,
                               acc[i][2] + bo.z, acc[i][3] + bo.w);
        *(float4*)(P0 + (size_t)t * SLOT + bb * 512 + nb) = r;
    }
}

// ---------------------------------------------------------------------------
// 3b) P1 = H0 @ W1x.T + b1  -> layout (T, B, N).  A rows are length 512.
// ---------------------------------------------------------------------------
__global__ __launch_bounds__(256) void gemm_p1(const float* __restrict__ H0,
                                               const float* __restrict__ W1,
                                               const float* __restrict__ b1v,
                                               float* __restrict__ P1) {
    __shared__ float As[32][68];   // [k][b]
    __shared__ float Ws[32][68];   // [k][n]
    int t = blockIdx.y;
    int n0 = blockIdx.x * 64;
    int tid = threadIdx.x;
    int bq = tid & 15;
    int nq = tid >> 4;
    const float* A = H0 + (size_t)t * SLOT;
    float acc[4][4] = {{0.f}};     // [b][n]

    for (int kc = 0; kc < 512; kc += 32) {
        for (int i = tid; i < 512; i += 256) {
            int bb = i >> 3, kq = i & 7;
            float4 a = *(const float4*)(A + bb * 512 + kc + kq * 4);
            As[kq*4+0][bb] = a.x; As[kq*4+1][bb] = a.y;
            As[kq*4+2][bb] = a.z; As[kq*4+3][bb] = a.w;
        }
        for (int i = tid; i < 512; i += 256) {
            int nn = i >> 3, kq = i & 7;
            float4 w = *(const float4*)(W1 + (size_t)(n0 + nn) * 1024 + kc + kq * 4);
            Ws[kq*4+0][nn] = w.x; Ws[kq*4+1][nn] = w.y;
            Ws[kq*4+2][nn] = w.z; Ws[kq*4+3][nn] = w.w;
        }
        __syncthreads();
#pragma unroll
        for (int kk = 0; kk < 32; kk++) {
            float4 a = *(const float4*)&As[kk][bq * 4];
            float4 w = *(const float4*)&Ws[kk][nq * 4];
            acc[0][0] += a.x*w.x; acc[0][1] += a.x*w.y; acc[0][2] += a.x*w.z; acc[0][3] += a.x*w.w;
            acc[1][0] += a.y*w.x; acc[1][1] += a.y*w.y; acc[1][2] += a.y*w.z; acc[1][3] += a.y*w.w;
            acc[2][0] += a.z*w.x; acc[2][1] += a.z*w.y; acc[2][2] += a.z*w.z; acc[2][3] += a.z*w.w;
            acc[3][0] += a.w*w.x; acc[3][1] += a.w*w.y; acc[3][2] += a.w*w.z; acc[3][3] += a.w*w.w;
        }
        __syncthreads();
    }
    int nb = n0 + nq * 4;
    float4 bo = *(const float4*)(b1v + nb);
#pragma unroll
    for (int i = 0; i < 4; i++) {
        int bb = bq * 4 + i;
        float4 r = make_float4(acc[i][0] + bo.x, acc[i][1] + bo.y,
                               acc[i][2] + bo.z, acc[i][3] + bo.w);
        *(float4*)(P1 + (size_t)t * SLOT + bb * 512 + nb) = r;
    }
}

// ---------------------------------------------------------------------------
// 4) Hybrid-resident single-layer recurrence (unchanged structure).
//    Layer 1 writes its history directly as split bf16 (hi/lo) for the MFMA
//    logits GEMM — numerically identical to a separate split pass.
// ---------------------------------------------------------------------------
#define RPT32(X) X(0) X(1) X(2) X(3) X(4) X(5) X(6) X(7) X(8) X(9) X(10) X(11) \
  X(12) X(13) X(14) X(15) X(16) X(17) X(18) X(19) X(20) X(21) X(22) X(23) \
  X(24) X(25) X(26) X(27) X(28) X(29) X(30) X(31)
#define RPT16P(X) X(0,0,1) X(1,2,3) X(2,4,5) X(3,6,7) X(4,8,9) X(5,10,11) \
  X(6,12,13) X(7,14,15) X(8,16,17) X(9,18,19) X(10,20,21) X(11,22,23) \
  X(12,24,25) X(13,26,27) X(14,28,29) X(15,30,31)

__global__ __launch_bounds__(512, 2) void chain_hyb(const float* __restrict__ P,
                                                    const float* __restrict__ hidden,
                                                    const float* __restrict__ Wp,
                                                    float* __restrict__ Hist,
                                                    unsigned short* __restrict__ Hhi,
                                                    unsigned short* __restrict__ Hlo,
                                                    float* __restrict__ out,
                                                    int layer) {
    __shared__ float lds_w[WL_F];     // 112 KB: [hq][jr][n]
    __shared__ float hs[512];
    __shared__ float2 part2[256];
    int tid = threadIdx.x;
    int b   = blockIdx.x;
    int n2  = tid & 255;
    int hq  = tid >> 8;               // wave-uniform
    int n0  = 2 * n2;

    // ---- one-time: VGPR section into 32 NAMED float4 registers ----
    const float4* wv = (const float4*)Wp + hq * (32 * 256) + n2;
#define DECLW(i) const float4 w##i = wv[(i) * 256];
    RPT32(DECLW)
#undef DECLW

    // ---- one-time: LDS section ----
    {
        const float4* wl4 = (const float4*)(Wp + WV_F);
        float4* l4 = (float4*)lds_w;
        for (int i = tid; i < WL_F / 4; i += 512) l4[i] = wl4[i];
    }
    hs[tid & 511] = hidden[layer * SLOT + b * 512 + (tid & 511)];
    __syncthreads();

    const float4* wsp = (const float4*)(Wp + WV_F + WL_F) + hq * (82 * 256) + n2;
    const float4* hs4 = (const float4*)hs;
    const float2* ldsw2 = (const float2*)lds_w;
    int hql4 = hq * 64;               // hs4 base for VGPR section
    int ksb  = hq * 256 + 92;         // hs base for streamed section

    for (int s = 0; s < T; s++) {
        float2 pin = make_float2(0.f, 0.f);
        if (hq == 0)
            pin = *(const float2*)(P + (size_t)s * SLOT + b * 512 + n0);

        float ax = 0.f, ay = 0.f;

        // streamed section first: loads issue early, FMAs below hide latency
#pragma unroll 16
        for (int j = 0; j < 82; j++) {
            float4 wv4 = wsp[j * 256];
            float2 h2 = *(const float2*)&hs[ksb + 2 * j];
            ax += wv4.x * h2.x + wv4.z * h2.y;
            ay += wv4.y * h2.x + wv4.w * h2.y;
        }

        // VGPR-resident section (no memory traffic)
#define FMAV(m, A, B2) { float4 h4 = hs4[hql4 + (m)]; \
        ax += w##A.x * h4.x + w##A.z * h4.y + w##B2.x * h4.z + w##B2.z * h4.w; \
        ay += w##A.y * h4.x + w##A.w * h4.y + w##B2.y * h4.z + w##B2.w * h4.w; }
        RPT16P(FMAV)
#undef FMAV

        // LDS-resident section
#pragma unroll
        for (int g = 0; g < 7; g++) {
            float4 h4 = hs4[hql4 + 16 + g];
            float2 l0 = ldsw2[(hq * 28 + 4 * g + 0) * 256 + n2];
            float2 l1 = ldsw2[(hq * 28 + 4 * g + 1) * 256 + n2];
            float2 l2 = ldsw2[(hq * 28 + 4 * g + 2) * 256 + n2];
            float2 l3 = ldsw2[(hq * 28 + 4 * g + 3) * 256 + n2];
            ax += l0.x * h4.x + l1.x * h4.y + l2.x * h4.z + l3.x * h4.w;
            ay += l0.y * h4.x + l1.y * h4.y + l2.y * h4.z + l3.y * h4.w;
        }

        if (hq) part2[n2] = make_float2(ax, ay);
        __syncthreads();
        if (hq == 0) {
            float2 pr = part2[n2];
            float o0 = ftanh(pin.x + ax + pr.x);
            float o1 = ftanh(pin.y + ay + pr.y);
            hs[n0] = o0; hs[n0 + 1] = o1;
            if (layer == 0) {
                *(float2*)(Hist + (size_t)s * SLOT + b * 512 + n0) = make_float2(o0, o1);
            } else {
                size_t m = (size_t)(s * 64 + b) * 512 + n0;
                unsigned short h0 = f2bf(o0), h1 = f2bf(o1);
                Hhi[m] = h0;     Hhi[m + 1] = h1;
                Hlo[m] = f2bf(o0 - bf2f(h0));
                Hlo[m + 1] = f2bf(o1 - bf2f(h1));
            }
        }
        __syncthreads();
    }

    // final hidden -> d_out tail, (L,B,H) row-major
    out[LOGITS_N + layer * SLOT + b * 512 + tid] = hs[tid];
}

// ---------------------------------------------------------------------------
// 5) logits = tanh(H1 @ Wout.T + bout) via split-bf16 MFMA.
//    M = TB = 4480 (m = t*64+b), N = NP (padded 10112), K = 512.
//    x = hi + lo (bf16 each); a*b ~= ah*bh + ah*bl + al*bh  (lo*lo dropped,
//    ~4e-6 relative). fp32 accumulation inside MFMA.
//    Block: 256 thr = 4 waves, 128x128 tile; wave = 64x64 = 4x4 frags of
//    mfma_f32_16x16x32_bf16. LDS rows padded to 40 bf16 (80 B: 16-B aligned,
//    <=2-way bank aliasing = free).
//    Frag layouts (m89-verified family): A row = lane&15, k = (lane>>4)*8+j;
//    B col = lane&15, same k; C/D col = lane&15, row = (lane>>4)*4 + reg.
// ---------------------------------------------------------------------------
__global__ __launch_bounds__(256, 2) void logits_mfma(const unsigned short* __restrict__ Ahi,
                                                      const unsigned short* __restrict__ Alo,
                                                      const unsigned short* __restrict__ Whi,
                                                      const unsigned short* __restrict__ Wlo,
                                                      const float* __restrict__ boutv,
                                                      float* __restrict__ out) {
    __shared__ unsigned short Ah[128 * 40], Al[128 * 40];
    __shared__ unsigned short Bh[128 * 40], Bl[128 * 40];
    int tid = threadIdx.x;
    int v0 = blockIdx.x * 128;
    int mb = blockIdx.y * 128;
    int lane = tid & 63;
    int wid = tid >> 6;
    int lr = lane & 15;
    int lg = lane >> 4;
    int mhalf = (wid & 1) * 64;
    int nhalf = (wid >> 1) * 64;

    f32x4 acc[4][4];
#pragma unroll
    for (int i = 0; i < 4; i++)
#pragma unroll
        for (int j = 0; j < 4; j++) {
            acc[i][j][0] = 0.f; acc[i][j][1] = 0.f;
            acc[i][j][2] = 0.f; acc[i][j][3] = 0.f;
        }

    int aoff[4], boff[4];
#pragma unroll
    for (int f = 0; f < 4; f++) {
        aoff[f] = (mhalf + f * 16 + lr) * 40 + lg * 8;
        boff[f] = (nhalf + f * 16 + lr) * 40 + lg * 8;
    }

    for (int kb = 0; kb < 512; kb += 32) {
        // stage 128x32 of each matrix (hi/lo for A and B): 16B units
#pragma unroll
        for (int it = 0; it < 2; ++it) {
            int idx = it * 256 + tid;
            int r = idx >> 2, u = idx & 3;
            int d = r * 40 + u * 8;
            size_t sA = (size_t)(mb + r) * 512 + kb + u * 8;
            size_t sB = (size_t)(v0 + r) * 512 + kb + u * 8;
            *(uint4*)&Ah[d] = *(const uint4*)&Ahi[sA];
            *(uint4*)&Al[d] = *(const uint4*)&Alo[sA];
            *(uint4*)&Bh[d] = *(const uint4*)&Whi[sB];
            *(uint4*)&Bl[d] = *(const uint4*)&Wlo[sB];
        }
        __syncthreads();

        bh8 ah[4], al[4], bh[4], bl[4];
#pragma unroll
        for (int f = 0; f < 4; f++) {
            ah[f] = *(const bh8*)&Ah[aoff[f]];
            al[f] = *(const bh8*)&Al[aoff[f]];
            bh[f] = *(const bh8*)&Bh[boff[f]];
            bl[f] = *(const bh8*)&Bl[boff[f]];
        }
#pragma unroll
        for (int mf = 0; mf < 4; mf++)
#pragma unroll
            for (int nf = 0; nf < 4; nf++) {
                acc[mf][nf] = __builtin_amdgcn_mfma_f32_16x16x32_bf16(ah[mf], bh[nf], acc[mf][nf], 0, 0, 0);
                acc[mf][nf] = __builtin_amdgcn_mfma_f32_16x16x32_bf16(ah[mf], bl[nf], acc[mf][nf], 0, 0, 0);
                acc[mf][nf] = __builtin_amdgcn_mfma_f32_16x16x32_bf16(al[mf], bh[nf], acc[mf][nf], 0, 0, 0);
            }
        __syncthreads();
    }

    // epilogue: D col = lane&15, row = (lane>>4)*4 + reg
#pragma unroll
    for (int nf = 0; nf < 4; nf++) {
        int v = v0 + nhalf + nf * 16 + lr;
        if (v < V) {
            float bo = boutv[v];
#pragma unroll
            for (int mf = 0; mf < 4; mf++) {
                int gm = mb + mhalf + mf * 16 + lg * 4;
#pragma unroll
                for (int reg = 0; reg < 4; reg++)
                    out[(size_t)(gm + reg) * V + v] = ftanh(acc[mf][nf][reg] + bo);
            }
        }
    }
}

// ---------------------------------------------------------------------------
extern "C" void kernel_launch(void* const* d_in, const int* in_sizes, int n_in,
                              void* d_out, int out_size, void* d_ws, size_t ws_size,
                              hipStream_t stream) {
    const int*   ids    = (const int*)d_in[0];
    const float* hidden = (const float*)d_in[1];
    const float* emb    = (const float*)d_in[2];
    const float* W0     = (const float*)d_in[3];
    const float* b0v    = (const float*)d_in[4];
    const float* W1     = (const float*)d_in[5];
    const float* b1v    = (const float*)d_in[6];
    const float* Wout   = (const float*)d_in[7];
    const float* boutv  = (const float*)d_in[8];
    float* out = (float*)d_out;
    float* ws  = (float*)d_ws;

    // layout (floats):
    //   X    [0,        2293760)   later overlaid by P1
    //   P0   [2293760,  4587520)   later overlaid by H1hi/H1lo (bf16)
    //   H0   [4587520,  6881280)
    //   Wpk  [6881280,  7405568)
    //   Whi  [7405568,  9994240)   NP*512 ushort
    //   Wlo  [9994240, 12582912)   NP*512 ushort    total 50.3 MB
    float* X    = ws;
    float* P0   = ws + 2293760;
    float* H0   = ws + 4587520;
    float* Wpk  = ws + 6881280;
    float* P1   = X;
    unsigned short* H1hi = (unsigned short*)(ws + 2293760);
    unsigned short* H1lo = (unsigned short*)(ws + 2293760 + 1146880);
    unsigned short* Whi  = (unsigned short*)(ws + 7405568);
    unsigned short* Wlo  = (unsigned short*)(ws + 9994240);

    gather_emb<<<2240, 256, 0, stream>>>(ids, emb, X);
    pack_w<<<680, 256, 0, stream>>>(W0, W1, Wpk);
    split_w<<<(NP * 512) / 256, 256, 0, stream>>>(Wout, Whi, Wlo);
    gemm_p0<<<dim3(8, T), 256, 0, stream>>>(X, W0, b0v, P0);
    chain_hyb<<<64, 512, 0, stream>>>(P0, hidden, Wpk, H0, nullptr, nullptr, out, 0);
    gemm_p1<<<dim3(8, T), 256, 0, stream>>>(H0, W1, b1v, P1);
    chain_hyb<<<64, 512, 0, stream>>>(P1, hidden, Wpk + WLAYER, nullptr, H1hi, H1lo, out, 1);
    logits_mfma<<<dim3(NP / 128, TB / 128), 256, 0, stream>>>(H1hi, H1lo, Whi, Wlo, boutv, out);
}

// Round 7
// 1336.699 us; speedup vs baseline: 3.1197x; 1.0382x over previous
//
#include <hip/hip_runtime.h>

// Sizes
#define T 70
#define B 64
#define E 512
#define H 512
#define V 10000
#define NP 10112            // V padded to 79*128 for the MFMA logits GEMM
#define TB (T*B)            // 4480
#define SLOT (H*B)          // 32768 floats per (t) state slot
#define LOGITS_N (T*B*V)    // 44800000

// chain_hyb weight partition (per 256-k half, per layer):
//   k-offsets [0,80)    -> VGPR   (40 float4/thread pinned, 160 VGPR, 320 KB/layer)
//   k-offsets [80,116)  -> LDS    (36 rows x 512 n x 2 halves = 144 KB)
//   k-offsets [116,256) -> stream (70 float4/thread/step, 573 KB/layer)
#define WV_F 81920          // floats in VGPR section  (2*40*256 float4)
#define WL_F 36864          // floats in LDS section   (2*36*512)
#define WS_F4 35840         // float4 in stream section (2*70*256)
#define WLAYER 262144       // floats per layer (1 MB)

typedef __attribute__((ext_vector_type(8))) short bh8;   // 8 bf16 (4 VGPRs)
typedef __attribute__((ext_vector_type(4))) float f32x4; // MFMA accumulator

__device__ __forceinline__ float ftanh(float x) {
    // tanh(x) = 1 - 2/(exp(2x)+1); saturates correctly at +/-inf
    float e = __expf(2.0f * x);
    return 1.0f - 2.0f / (e + 1.0f);
}

__device__ __forceinline__ unsigned short f2bf(float x) {  // RNE fp32->bf16
    unsigned int u = __float_as_uint(x);
    u += 0x7FFFu + ((u >> 16) & 1u);
    return (unsigned short)(u >> 16);
}
__device__ __forceinline__ float bf2f(unsigned short h) {
    return __uint_as_float(((unsigned int)h) << 16);
}

// ---------------------------------------------------------------------------
// 1) Embedding gather: X[t][b][e] (row-major) = emb_table[ids[t][b]][e]
// ---------------------------------------------------------------------------
__global__ __launch_bounds__(256) void gather_emb(const int* __restrict__ ids,
                                                  const float* __restrict__ emb,
                                                  float* __restrict__ X) {
    int i = blockIdx.x * 256 + threadIdx.x;       // float4 index
    if (i >= TB * (E / 4)) return;
    int tok = i >> 7;                             // E/4 = 128 float4 per token
    int e4 = i & 127;
    int id = ids[tok];
    ((float4*)X)[i] = ((const float4*)emb)[id * 128 + e4];
}

// ---------------------------------------------------------------------------
// 2) One-time pack of the recurrent weight halves W{0,1}[n][512+k] into the
//    three chain_hyb sections (all destinations linear for L2 streaming):
//    Wv: [hq][j2<40][n2] float4 {W(n0,k),W(n1,k),W(n0,k+1),W(n1,k+1)}, k=hq*256+2*j2
//    Ws: [hq][j2s<70][n2] float4, k = hq*256+116+2*j2s
//    Wl: [hq][jr<36][n]  float,  k = hq*256+80+jr
// ---------------------------------------------------------------------------
__global__ __launch_bounds__(256) void pack_w(const float* __restrict__ W0,
                                              const float* __restrict__ W1,
                                              float* __restrict__ Wpk) {
    int g = blockIdx.x * 256 + threadIdx.x;       // [0, 186368)
    int l = g >= 93184;
    int u = g - l * 93184;
    const float* S = l ? W1 : W0;
    float* D = Wpk + l * WLAYER;

    if (u < 20480) {                              // Wv float4 units
        int n2 = u & 255, q = u >> 8;             // q in [0,80) = hq*40 + j2
        int j2 = q % 40, hq = q / 40;
        int k = hq * 256 + 2 * j2;
        int n0 = 2 * n2;
        float2 r0 = *(const float2*)(S + (size_t)n0 * 1024 + 512 + k);
        float2 r1 = *(const float2*)(S + (size_t)(n0 + 1) * 1024 + 512 + k);
        ((float4*)D)[(hq * 40 + j2) * 256 + n2] = make_float4(r0.x, r1.x, r0.y, r1.y);
    } else if (u < 20480 + WS_F4) {               // Ws float4 units
        int v = u - 20480;
        int n2 = v & 255, q = v >> 8;             // q in [0,140) = hq*70 + j2s
        int j2s = q % 70, hq = q / 70;
        int k = hq * 256 + 116 + 2 * j2s;
        int n0 = 2 * n2;
        float2 r0 = *(const float2*)(S + (size_t)n0 * 1024 + 512 + k);
        float2 r1 = *(const float2*)(S + (size_t)(n0 + 1) * 1024 + 512 + k);
        ((float4*)D)[(WV_F + WL_F) / 4 + (hq * 70 + j2s) * 256 + n2] =
            make_float4(r0.x, r1.x, r0.y, r1.y);
    } else {                                      // Wl scalar units
        int w = u - (20480 + WS_F4);              // [0, 36864)
        int n = w & 511, q = w >> 9;              // q in [0,72) = hq*36 + jr
        int jr = q % 36, hq = q / 36;
        int k = hq * 256 + 80 + jr;
        D[WV_F + (hq * 36 + jr) * 512 + n] = S[(size_t)n * 1024 + 512 + k];
    }
}

// ---------------------------------------------------------------------------
// 2b) One-time split of Wout (fp32 [V][512]) into bf16 hi/lo, zero-padded to
//     [NP][512] rows so the MFMA GEMM needs no N-guard in its inner loop.
// ---------------------------------------------------------------------------
__global__ __launch_bounds__(256) void split_w(const float* __restrict__ Wout,
                                               unsigned short* __restrict__ Whi,
                                               unsigned short* __restrict__ Wlo) {
    int i = blockIdx.x * 256 + threadIdx.x;       // [0, NP*512)
    if (i >= NP * 512) return;
    int v = i >> 9;
    float x = (v < V) ? Wout[i] : 0.f;
    unsigned short hi = f2bf(x);
    Whi[i] = hi;
    Wlo[i] = f2bf(x - bf2f(hi));
}

// ---------------------------------------------------------------------------
// 3) P0 = X @ W0x.T + b0   -> layout (T, B=64, N=512)  [n contiguous]
// ---------------------------------------------------------------------------
__global__ __launch_bounds__(256) void gemm_p0(const float* __restrict__ X,
                                               const float* __restrict__ W0,
                                               const float* __restrict__ b0v,
                                               float* __restrict__ P0) {
    __shared__ float As[32][68];   // [k][b]
    __shared__ float Ws[32][68];   // [k][n]
    int t = blockIdx.y;
    int n0 = blockIdx.x * 64;
    int tid = threadIdx.x;
    int bq = tid & 15;    // b block = bq*4
    int nq = tid >> 4;    // n local = nq*4
    const float* A = X + t * 64 * E;
    float acc[4][4] = {{0.f}};     // [b][n]

    for (int kc = 0; kc < 512; kc += 32) {
        for (int i = tid; i < 512; i += 256) {
            int bb = i >> 3, kq = i & 7;
            float4 a = *(const float4*)(A + bb * E + kc + kq * 4);
            As[kq*4+0][bb] = a.x; As[kq*4+1][bb] = a.y;
            As[kq*4+2][bb] = a.z; As[kq*4+3][bb] = a.w;
        }
        for (int i = tid; i < 512; i += 256) {
            int nn = i >> 3, kq = i & 7;
            float4 w = *(const float4*)(W0 + (size_t)(n0 + nn) * 1024 + kc + kq * 4);
            Ws[kq*4+0][nn] = w.x; Ws[kq*4+1][nn] = w.y;
            Ws[kq*4+2][nn] = w.z; Ws[kq*4+3][nn] = w.w;
        }
        __syncthreads();
#pragma unroll
        for (int kk = 0; kk < 32; kk++) {
            float4 a = *(const float4*)&As[kk][bq * 4];
            float4 w = *(const float4*)&Ws[kk][nq * 4];
            acc[0][0] += a.x*w.x; acc[0][1] += a.x*w.y; acc[0][2] += a.x*w.z; acc[0][3] += a.x*w.w;
            acc[1][0] += a.y*w.x; acc[1][1] += a.y*w.y; acc[1][2] += a.y*w.z; acc[1][3] += a.y*w.w;
            acc[2][0] += a.z*w.x; acc[2][1] += a.z*w.y; acc[2][2] += a.z*w.z; acc[2][3] += a.z*w.w;
            acc[3][0] += a.w*w.x; acc[3][1] += a.w*w.y; acc[3][2] += a.w*w.z; acc[3][3] += a.w*w.w;
        }
        __syncthreads();
    }
    int nb = n0 + nq * 4;
    float4 bo = *(const float4*)(b0v + nb);
#pragma unroll
    for (int i = 0; i < 4; i++) {
        int bb = bq * 4 + i;
        float4 r = make_float4(acc[i][0] + bo.x, acc[i][1] + bo.y,
                               acc[i][2] + bo.z, acc[i][3] + bo.w);
        *(float4*)(P0 + (size_t)t * SLOT + bb * 512 + nb) = r;
    }
}

// ---------------------------------------------------------------------------
// 3b) P1 = H0 @ W1x.T + b1  -> layout (T, B, N).  A rows are length 512.
// ---------------------------------------------------------------------------
__global__ __launch_bounds__(256) void gemm_p1(const float* __restrict__ H0,
                                               const float* __restrict__ W1,
                                               const float* __restrict__ b1v,
                                               float* __restrict__ P1) {
    __shared__ float As[32][68];   // [k][b]
    __shared__ float Ws[32][68];   // [k][n]
    int t = blockIdx.y;
    int n0 = blockIdx.x * 64;
    int tid = threadIdx.x;
    int bq = tid & 15;
    int nq = tid >> 4;
    const float* A = H0 + (size_t)t * SLOT;
    float acc[4][4] = {{0.f}};     // [b][n]

    for (int kc = 0; kc < 512; kc += 32) {
        for (int i = tid; i < 512; i += 256) {
            int bb = i >> 3, kq = i & 7;
            float4 a = *(const float4*)(A + bb * 512 + kc + kq * 4);
            As[kq*4+0][bb] = a.x; As[kq*4+1][bb] = a.y;
            As[kq*4+2][bb] = a.z; As[kq*4+3][bb] = a.w;
        }
        for (int i = tid; i < 512; i += 256) {
            int nn = i >> 3, kq = i & 7;
            float4 w = *(const float4*)(W1 + (size_t)(n0 + nn) * 1024 + kc + kq * 4);
            Ws[kq*4+0][nn] = w.x; Ws[kq*4+1][nn] = w.y;
            Ws[kq*4+2][nn] = w.z; Ws[kq*4+3][nn] = w.w;
        }
        __syncthreads();
#pragma unroll
        for (int kk = 0; kk < 32; kk++) {
            float4 a = *(const float4*)&As[kk][bq * 4];
            float4 w = *(const float4*)&Ws[kk][nq * 4];
            acc[0][0] += a.x*w.x; acc[0][1] += a.x*w.y; acc[0][2] += a.x*w.z; acc[0][3] += a.x*w.w;
            acc[1][0] += a.y*w.x; acc[1][1] += a.y*w.y; acc[1][2] += a.y*w.z; acc[1][3] += a.y*w.w;
            acc[2][0] += a.z*w.x; acc[2][1] += a.z*w.y; acc[2][2] += a.z*w.z; acc[2][3] += a.z*w.w;
            acc[3][0] += a.w*w.x; acc[3][1] += a.w*w.y; acc[3][2] += a.w*w.z; acc[3][3] += a.w*w.w;
        }
        __syncthreads();
    }
    int nb = n0 + nq * 4;
    float4 bo = *(const float4*)(b1v + nb);
#pragma unroll
    for (int i = 0; i < 4; i++) {
        int bb = bq * 4 + i;
        float4 r = make_float4(acc[i][0] + bo.x, acc[i][1] + bo.y,
                               acc[i][2] + bo.z, acc[i][3] + bo.w);
        *(float4*)(P1 + (size_t)t * SLOT + bb * 512 + nb) = r;
    }
}

// ---------------------------------------------------------------------------
// 4) Hybrid-resident single-layer recurrence. Weights: 160 VGPRs PINNED via
//    asm (prevents the compiler from sinking the loads into the s-loop, which
//    round-6 counters proved it did: VGPR_Count=120 < the 128 required),
//    144 KB LDS, 573 KB/step streamed from L2.
// ---------------------------------------------------------------------------
#define RPT40(X) X(0) X(1) X(2) X(3) X(4) X(5) X(6) X(7) X(8) X(9) X(10) X(11) \
  X(12) X(13) X(14) X(15) X(16) X(17) X(18) X(19) X(20) X(21) X(22) X(23) \
  X(24) X(25) X(26) X(27) X(28) X(29) X(30) X(31) X(32) X(33) X(34) X(35) \
  X(36) X(37) X(38) X(39)
#define RPT20P(X) X(0,0,1) X(1,2,3) X(2,4,5) X(3,6,7) X(4,8,9) X(5,10,11) \
  X(6,12,13) X(7,14,15) X(8,16,17) X(9,18,19) X(10,20,21) X(11,22,23) \
  X(12,24,25) X(13,26,27) X(14,28,29) X(15,30,31) X(16,32,33) X(17,34,35) \
  X(18,36,37) X(19,38,39)

__global__ __launch_bounds__(512, 2) void chain_hyb(const float* __restrict__ P,
                                                    const float* __restrict__ hidden,
                                                    const float* __restrict__ Wp,
                                                    float* __restrict__ Hist,
                                                    unsigned short* __restrict__ Hhi,
                                                    unsigned short* __restrict__ Hlo,
                                                    float* __restrict__ out,
                                                    int layer) {
    __shared__ float lds_w[WL_F];     // 144 KB: [hq][jr][n]
    __shared__ float hs[512];
    __shared__ float2 part2[256];
    int tid = threadIdx.x;
    int b   = blockIdx.x;
    int n2  = tid & 255;
    int hq  = tid >> 8;               // wave-uniform
    int n0  = 2 * n2;

    // ---- one-time: VGPR section into 40 NAMED float4 registers ----
    const float4* wv = (const float4*)Wp + hq * (40 * 256) + n2;
#define DECLW(i) float4 w##i = wv[(i) * 256];
    RPT40(DECLW)
#undef DECLW

    // ---- one-time: LDS section ----
    {
        const float4* wl4 = (const float4*)(Wp + WV_F);
        float4* l4 = (float4*)lds_w;
        for (int i = tid; i < WL_F / 4; i += 512) l4[i] = wl4[i];
    }
    hs[tid & 511] = hidden[layer * SLOT + b * 512 + (tid & 511)];

    // pin the weight registers: the asm may modify them, so the loads above
    // cannot be rematerialized inside the loop (round-6 failure mode)
#define PINW(i) asm volatile("" : "+v"(w##i.x), "+v"(w##i.y), "+v"(w##i.z), "+v"(w##i.w));
    RPT40(PINW)
#undef PINW
    __syncthreads();

    const float4* wsp = (const float4*)(Wp + WV_F + WL_F) + hq * (70 * 256) + n2;
    const float4* hs4 = (const float4*)hs;
    const float2* ldsw2 = (const float2*)lds_w;
    int hql4 = hq * 64;               // hs4 base for this k-half
    int ksb  = hq * 256 + 116;        // hs base for streamed section

    for (int s = 0; s < T; s++) {
        float2 pin = make_float2(0.f, 0.f);
        if (hq == 0)
            pin = *(const float2*)(P + (size_t)s * SLOT + b * 512 + n0);

        float ax = 0.f, ay = 0.f;

        // streamed section first: loads issue early, FMAs below hide latency
#pragma unroll 8
        for (int j = 0; j < 70; j++) {
            float4 wv4 = wsp[j * 256];
            float2 h2 = *(const float2*)&hs[ksb + 2 * j];
            ax += wv4.x * h2.x + wv4.z * h2.y;
            ay += wv4.y * h2.x + wv4.w * h2.y;
        }

        // VGPR-resident section (no memory traffic): k = hq*256 + [0,80)
#define FMAV(m, A, B2) { float4 h4 = hs4[hql4 + (m)]; \
        ax += w##A.x * h4.x + w##A.z * h4.y + w##B2.x * h4.z + w##B2.z * h4.w; \
        ay += w##A.y * h4.x + w##A.w * h4.y + w##B2.y * h4.z + w##B2.w * h4.w; }
        RPT20P(FMAV)
#undef FMAV

        // LDS-resident section: k = hq*256 + [80,116)
#pragma unroll
        for (int g = 0; g < 9; g++) {
            float4 h4 = hs4[hql4 + 20 + g];
            float2 l0 = ldsw2[(hq * 36 + 4 * g + 0) * 256 + n2];
            float2 l1 = ldsw2[(hq * 36 + 4 * g + 1) * 256 + n2];
            float2 l2 = ldsw2[(hq * 36 + 4 * g + 2) * 256 + n2];
            float2 l3 = ldsw2[(hq * 36 + 4 * g + 3) * 256 + n2];
            ax += l0.x * h4.x + l1.x * h4.y + l2.x * h4.z + l3.x * h4.w;
            ay += l0.y * h4.x + l1.y * h4.y + l2.y * h4.z + l3.y * h4.w;
        }

        if (hq) part2[n2] = make_float2(ax, ay);
        __syncthreads();
        if (hq == 0) {
            float2 pr = part2[n2];
            float o0 = ftanh(pin.x + ax + pr.x);
            float o1 = ftanh(pin.y + ay + pr.y);
            hs[n0] = o0; hs[n0 + 1] = o1;
            if (layer == 0) {
                *(float2*)(Hist + (size_t)s * SLOT + b * 512 + n0) = make_float2(o0, o1);
            } else {
                size_t m = (size_t)(s * 64 + b) * 512 + n0;
                unsigned short h0 = f2bf(o0), h1 = f2bf(o1);
                Hhi[m] = h0;     Hhi[m + 1] = h1;
                Hlo[m] = f2bf(o0 - bf2f(h0));
                Hlo[m + 1] = f2bf(o1 - bf2f(h1));
            }
        }
        __syncthreads();
    }

    // final hidden -> d_out tail, (L,B,H) row-major
    out[LOGITS_N + layer * SLOT + b * 512 + tid] = hs[tid];
}

// ---------------------------------------------------------------------------
// 5) logits = tanh(H1 @ Wout.T + bout) via split-bf16 MFMA.
//    M = TB = 4480 (m = t*64+b), N = NP (padded 10112), K = 512.
//    x = hi + lo (bf16 each); a*b ~= ah*bh + ah*bl + al*bh  (lo*lo dropped).
// ---------------------------------------------------------------------------
__global__ __launch_bounds__(256, 2) void logits_mfma(const unsigned short* __restrict__ Ahi,
                                                      const unsigned short* __restrict__ Alo,
                                                      const unsigned short* __restrict__ Whi,
                                                      const unsigned short* __restrict__ Wlo,
                                                      const float* __restrict__ boutv,
                                                      float* __restrict__ out) {
    __shared__ unsigned short Ah[128 * 40], Al[128 * 40];
    __shared__ unsigned short Bh[128 * 40], Bl[128 * 40];
    int tid = threadIdx.x;
    int v0 = blockIdx.x * 128;
    int mb = blockIdx.y * 128;
    int lane = tid & 63;
    int wid = tid >> 6;
    int lr = lane & 15;
    int lg = lane >> 4;
    int mhalf = (wid & 1) * 64;
    int nhalf = (wid >> 1) * 64;

    f32x4 acc[4][4];
#pragma unroll
    for (int i = 0; i < 4; i++)
#pragma unroll
        for (int j = 0; j < 4; j++) {
            acc[i][j][0] = 0.f; acc[i][j][1] = 0.f;
            acc[i][j][2] = 0.f; acc[i][j][3] = 0.f;
        }

    int aoff[4], boff[4];
#pragma unroll
    for (int f = 0; f < 4; f++) {
        aoff[f] = (mhalf + f * 16 + lr) * 40 + lg * 8;
        boff[f] = (nhalf + f * 16 + lr) * 40 + lg * 8;
    }

    for (int kb = 0; kb < 512; kb += 32) {
        // stage 128x32 of each matrix (hi/lo for A and B): 16B units
#pragma unroll
        for (int it = 0; it < 2; ++it) {
            int idx = it * 256 + tid;
            int r = idx >> 2, u = idx & 3;
            int d = r * 40 + u * 8;
            size_t sA = (size_t)(mb + r) * 512 + kb + u * 8;
            size_t sB = (size_t)(v0 + r) * 512 + kb + u * 8;
            *(uint4*)&Ah[d] = *(const uint4*)&Ahi[sA];
            *(uint4*)&Al[d] = *(const uint4*)&Alo[sA];
            *(uint4*)&Bh[d] = *(const uint4*)&Whi[sB];
            *(uint4*)&Bl[d] = *(const uint4*)&Wlo[sB];
        }
        __syncthreads();

        bh8 ah[4], al[4], bh[4], bl[4];
#pragma unroll
        for (int f = 0; f < 4; f++) {
            ah[f] = *(const bh8*)&Ah[aoff[f]];
            al[f] = *(const bh8*)&Al[aoff[f]];
            bh[f] = *(const bh8*)&Bh[boff[f]];
            bl[f] = *(const bh8*)&Bl[boff[f]];
        }
#pragma unroll
        for (int mf = 0; mf < 4; mf++)
#pragma unroll
            for (int nf = 0; nf < 4; nf++) {
                acc[mf][nf] = __builtin_amdgcn_mfma_f32_16x16x32_bf16(ah[mf], bh[nf], acc[mf][nf], 0, 0, 0);
                acc[mf][nf] = __builtin_amdgcn_mfma_f32_16x16x32_bf16(ah[mf], bl[nf], acc[mf][nf], 0, 0, 0);
                acc[mf][nf] = __builtin_amdgcn_mfma_f32_16x16x32_bf16(al[mf], bh[nf], acc[mf][nf], 0, 0, 0);
            }
        __syncthreads();
    }

    // epilogue: D col = lane&15, row = (lane>>4)*4 + reg
#pragma unroll
    for (int nf = 0; nf < 4; nf++) {
        int v = v0 + nhalf + nf * 16 + lr;
        if (v < V) {
            float bo = boutv[v];
#pragma unroll
            for (int mf = 0; mf < 4; mf++) {
                int gm = mb + mhalf + mf * 16 + lg * 4;
#pragma unroll
                for (int reg = 0; reg < 4; reg++)
                    out[(size_t)(gm + reg) * V + v] = ftanh(acc[mf][nf][reg] + bo);
            }
        }
    }
}

// ---------------------------------------------------------------------------
extern "C" void kernel_launch(void* const* d_in, const int* in_sizes, int n_in,
                              void* d_out, int out_size, void* d_ws, size_t ws_size,
                              hipStream_t stream) {
    const int*   ids    = (const int*)d_in[0];
    const float* hidden = (const float*)d_in[1];
    const float* emb    = (const float*)d_in[2];
    const float* W0     = (const float*)d_in[3];
    const float* b0v    = (const float*)d_in[4];
    const float* W1     = (const float*)d_in[5];
    const float* b1v    = (const float*)d_in[6];
    const float* Wout   = (const float*)d_in[7];
    const float* boutv  = (const float*)d_in[8];
    float* out = (float*)d_out;
    float* ws  = (float*)d_ws;

    // layout (floats):
    //   X    [0,        2293760)   later overlaid by P1
    //   P0   [2293760,  4587520)   later overlaid by H1hi/H1lo (bf16)
    //   H0   [4587520,  6881280)
    //   Wpk  [6881280,  7405568)
    //   Whi  [7405568,  9994240)   NP*512 ushort
    //   Wlo  [9994240, 12582912)   NP*512 ushort    total 50.3 MB
    float* X    = ws;
    float* P0   = ws + 2293760;
    float* H0   = ws + 4587520;
    float* Wpk  = ws + 6881280;
    float* P1   = X;
    unsigned short* H1hi = (unsigned short*)(ws + 2293760);
    unsigned short* H1lo = (unsigned short*)(ws + 2293760 + 1146880);
    unsigned short* Whi  = (unsigned short*)(ws + 7405568);
    unsigned short* Wlo  = (unsigned short*)(ws + 9994240);

    gather_emb<<<2240, 256, 0, stream>>>(ids, emb, X);
    pack_w<<<728, 256, 0, stream>>>(W0, W1, Wpk);
    split_w<<<(NP * 512) / 256, 256, 0, stream>>>(Wout, Whi, Wlo);
    gemm_p0<<<dim3(8, T), 256, 0, stream>>>(X, W0, b0v, P0);
    chain_hyb<<<64, 512, 0, stream>>>(P0, hidden, Wpk, H0, nullptr, nullptr, out, 0);
    gemm_p1<<<dim3(8, T), 256, 0, stream>>>(H0, W1, b1v, P1);
    chain_hyb<<<64, 512, 0, stream>>>(P1, hidden, Wpk + WLAYER, nullptr, H1hi, H1lo, out, 1);
    logits_mfma<<<dim3(NP / 128, TB / 128), 256, 0, stream>>>(H1hi, H1lo, Whi, Wlo, boutv, out);
}